// Round 5
// baseline (1105.138 us; speedup 1.0000x reference)
//
#include <hip/hip_runtime.h>
#include <cmath>

typedef __bf16 bf16_t;
typedef __bf16 bf16x8 __attribute__((ext_vector_type(8)));
typedef float  f32x4  __attribute__((ext_vector_type(4)));

#define SEQ    2048
#define HID    4096
#define QKV_N  6144
#define NH     32
#define NKV    8
#define HD     128
#define ATT_SCALE 0.08838834764831845f

__device__ __forceinline__ f32x4 mfma16(bf16x8 a, bf16x8 b, f32x4 c) {
  return __builtin_amdgcn_mfma_f32_16x16x32_bf16(a, b, c, 0, 0, 0);
}

__device__ __forceinline__ void gload_lds16(const void* g, void* l) {
  __builtin_amdgcn_global_load_lds(
      (const __attribute__((address_space(1))) void*)g,
      (__attribute__((address_space(3))) void*)l, 16, 0, 0);
}

// ---------------- cast fp32 -> bf16 (vectorized) ----------------
__global__ __launch_bounds__(256) void cast_f32_bf16(
    const float* __restrict__ in, bf16_t* __restrict__ out, int n) {
  int i = (blockIdx.x * 256 + threadIdx.x) * 8;
  if (i >= n) return;
  float4 v0 = *(const float4*)(in + i);
  float4 v1 = *(const float4*)(in + i + 4);
  bf16x8 o;
  o[0] = (bf16_t)v0.x; o[1] = (bf16_t)v0.y; o[2] = (bf16_t)v0.z; o[3] = (bf16_t)v0.w;
  o[4] = (bf16_t)v1.x; o[5] = (bf16_t)v1.y; o[6] = (bf16_t)v1.z; o[7] = (bf16_t)v1.w;
  *(bf16x8*)(out + i) = o;
}

// ---------------- transpose + cast: in [R][C] f32 -> out [C][R] bf16 ----------------
__global__ __launch_bounds__(256) void transpose_cast(
    const float* __restrict__ in, bf16_t* __restrict__ out, int R, int C) {
  __shared__ float tile[32][33];
  int c0 = blockIdx.x * 32, r0 = blockIdx.y * 32;
  int x = threadIdx.x, y = threadIdx.y;   // 32 x 8
  for (int j = 0; j < 32; j += 8)
    tile[y + j][x] = in[(size_t)(r0 + y + j) * C + c0 + x];
  __syncthreads();
  for (int j = 0; j < 32; j += 8)
    out[(size_t)(c0 + y + j) * R + r0 + x] = (bf16_t)tile[x][y + j];
}

// ---------------- transpose V part of qkv (bf16): [s][5120+dcol] -> vt[dcol][s] ----------------
__global__ __launch_bounds__(256) void transpose_v(
    const bf16_t* __restrict__ qkv, bf16_t* __restrict__ vt) {
  __shared__ bf16_t tile[32][33];
  int c0 = blockIdx.x * 32, r0 = blockIdx.y * 32;  // c0: dcol, r0: s
  int x = threadIdx.x, y = threadIdx.y;
  for (int j = 0; j < 32; j += 8)
    tile[y + j][x] = qkv[(size_t)(r0 + y + j) * QKV_N + 5120 + c0 + x];
  __syncthreads();
  for (int j = 0; j < 32; j += 8)
    vt[(size_t)(c0 + y + j) * SEQ + r0 + x] = tile[x][y + j];
}

// ---------------- RoPE cos/sin tables ----------------
__global__ __launch_bounds__(256) void rope_tables(
    const int* __restrict__ pos, float* __restrict__ ct, float* __restrict__ st) {
  int idx = blockIdx.x * 256 + threadIdx.x;
  if (idx >= SEQ * 64) return;
  int s = idx >> 6, j = idx & 63;
  double inv = exp(-((double)(2 * j) / 128.0) * log(10000.0));
  double a = (double)pos[s] * inv;
  ct[idx] = (float)cos(a);
  st[idx] = (float)sin(a);
}

// ---------------- apply RoPE in-place to q,k columns of qkv ----------------
__global__ __launch_bounds__(256) void rope_apply(
    bf16_t* __restrict__ qkv, const float* __restrict__ ct, const float* __restrict__ st) {
  int idx = blockIdx.x * 256 + threadIdx.x;   // SEQ * 2560
  int s = idx / 2560, p = idx % 2560;
  int head = p >> 6, j = p & 63;              // heads 0..31 = q, 32..39 = k
  int base = (head < NH) ? head * HD : HID + (head - NH) * HD;
  size_t o1 = (size_t)s * QKV_N + base + j;
  float x1 = (float)qkv[o1], x2 = (float)qkv[o1 + 64];
  float c = ct[s * 64 + j], sn = st[s * 64 + j];
  qkv[o1]      = (bf16_t)(x1 * c - x2 * sn);
  qkv[o1 + 64] = (bf16_t)(x2 * c + x1 * sn);
}

// ---------------- GEMM: C[M][N] = A[M][K] * Bt[N][K]^T  (m97 structure + XCD swz) ----------------
template <typename OutT>
__global__ __launch_bounds__(256, 2) void gemm_bt(
    const bf16_t* __restrict__ A, const bf16_t* __restrict__ Bt,
    OutT* __restrict__ C, int M, int N, int K) {
  __shared__ bf16_t As[128 * 32];
  __shared__ bf16_t Bs[128 * 32];
  const int tid = threadIdx.x;
  const int wid = tid >> 6, lane = tid & 63;
  // XCD-aware bijective swizzle (grid count is a multiple of 8)
  const int gx = gridDim.x;
  const int nwg = gx * gridDim.y;
  const int flat = blockIdx.y * gx + blockIdx.x;
  const int swz = (flat & 7) * (nwg >> 3) + (flat >> 3);
  const int m0 = (swz / gx) * 128, n0 = (swz % gx) * 128;
  const int wr = (wid >> 1) * 64, wc = (wid & 1) * 64;
  const int lrow = lane & 15, lk = lane >> 4;
  f32x4 acc[4][4];
  for (int m = 0; m < 4; ++m)
    for (int n = 0; n < 4; ++n) acc[m][n] = f32x4{0.f, 0.f, 0.f, 0.f};

  for (int k0 = 0; k0 < K; k0 += 32) {
    for (int i = 0; i < 2; ++i) {
      int off = wid * 2048 + i * 1024 + lane * 16;  // byte offset in 8KB tile
      int row = off >> 6;                            // 64B per row (32 bf16)
      int kk = (off & 63) >> 1;                      // element col
      gload_lds16(A + (size_t)(m0 + row) * K + k0 + kk,
                  (char*)As + wid * 2048 + i * 1024);
      gload_lds16(Bt + (size_t)(n0 + row) * K + k0 + kk,
                  (char*)Bs + wid * 2048 + i * 1024);
    }
    __syncthreads();
    bf16x8 a[4], b[4];
    for (int m = 0; m < 4; ++m)
      a[m] = *(const bf16x8*)(As + (wr + m * 16 + lrow) * 32 + lk * 8);
    for (int n = 0; n < 4; ++n)
      b[n] = *(const bf16x8*)(Bs + (wc + n * 16 + lrow) * 32 + lk * 8);
    for (int m = 0; m < 4; ++m)
      for (int n = 0; n < 4; ++n)
        acc[m][n] = mfma16(a[m], b[n], acc[m][n]);
    __syncthreads();
  }
  for (int m = 0; m < 4; ++m)
    for (int n = 0; n < 4; ++n)
      for (int r = 0; r < 4; ++r) {
        int row = m0 + wr + m * 16 + lk * 4 + r;
        int col = n0 + wc + n * 16 + lrow;
        C[(size_t)row * N + col] = (OutT)acc[m][n][r];
      }
}

// ---------------- flash attention (causal, GQA) ----------------
// 2-wave blocks. Block handles paired q-units (p, 63-p) of 32 rows each ->
// constant compute per block. kvh = bid&7 pins each kv-head to one XCD L2.
// grid: 1024 x 128 threads. K/V staged in LDS (XOR-swizzled), prefetch via regs.
__global__ __launch_bounds__(128, 2) void flash_attn(
    const bf16_t* __restrict__ qkv, const bf16_t* __restrict__ vt,
    bf16_t* __restrict__ attn_out) {
  __shared__ bf16_t Ks[64 * 128];    // [kv][d], swizzled, 16KB
  __shared__ bf16_t Vs[128 * 64];    // [d][kv], swizzled, 16KB
  __shared__ bf16_t Ps[2][32 * 64];  // per-wave P, swizzled, 8KB
  const int bid = blockIdx.x;
  const int kvh = bid & 7;
  const int u = bid >> 3;
  const int h = kvh * 4 + (u & 3);
  const int p = u >> 2;              // 0..31
  const int jA = p, jB = 63 - p;     // paired q-units of 32 rows
  const int tA = (jA >> 1) + 1, tB = (jB >> 1) + 1;
  const int tid = threadIdx.x, wid = tid >> 6, lane = tid & 63;
  const int lrow = lane & 15, lk = lane >> 4;
  const int qbase[2] = {jA * 32 + wid * 16, jB * 32 + wid * 16};

  // staging decomposition (128 threads, 8 chunks each per tile)
  int krow[8], kcol[8], vrow[8], vcol[8];
  for (int i = 0; i < 8; ++i) {
    int c = tid + 128 * i;
    krow[i] = c >> 4; kcol[i] = c & 15;   // K: 64 rows x 16 chunks
    vrow[i] = c >> 3; vcol[i] = c & 7;    // V: 128 rows x 8 chunks
  }

  // Q in registers
  bf16x8 qreg[2][4];
  for (int m = 0; m < 2; ++m)
    for (int kd = 0; kd < 4; ++kd)
      qreg[m][kd] = *(const bf16x8*)(qkv + (size_t)(qbase[m] + lrow) * QKV_N +
                                     h * HD + kd * 32 + lk * 8);

  f32x4 acc[2][8];
  float mst[2][4], lst[2][4];
  for (int m = 0; m < 2; ++m) {
    for (int df = 0; df < 8; ++df) acc[m][df] = f32x4{0.f, 0.f, 0.f, 0.f};
    for (int r = 0; r < 4; ++r) { mst[m][r] = -1e30f; lst[m][r] = 0.f; }
  }

  bf16x8 kpre[8], vpre[8];
  // prologue: stage tile 0
  for (int i = 0; i < 8; ++i) {
    kpre[i] = *(const bf16x8*)(qkv + (size_t)krow[i] * QKV_N + HID + kvh * HD +
                               kcol[i] * 8);
    vpre[i] = *(const bf16x8*)(vt + (size_t)(kvh * HD + vrow[i]) * SEQ +
                               vcol[i] * 8);
  }
  for (int i = 0; i < 8; ++i) {
    *(bf16x8*)((char*)Ks + ((krow[i] * 256 + kcol[i] * 16) ^ ((krow[i] & 7) << 4))) = kpre[i];
    *(bf16x8*)((char*)Vs + ((vrow[i] * 128 + vcol[i] * 16) ^ ((vrow[i] & 7) << 4))) = vpre[i];
  }
  __syncthreads();

  for (int t = 0; t < tB; ++t) {
    const int kv0 = t * 64;
    const bool haveNext = (t + 1 < tB);
    if (haveNext) {
      const int nkv0 = kv0 + 64;
      for (int i = 0; i < 8; ++i) {
        kpre[i] = *(const bf16x8*)(qkv + (size_t)(nkv0 + krow[i]) * QKV_N + HID +
                                   kvh * HD + kcol[i] * 8);
        vpre[i] = *(const bf16x8*)(vt + (size_t)(kvh * HD + vrow[i]) * SEQ +
                                   nkv0 + vcol[i] * 8);
      }
    }
    const bool actA = (t < tA);

    // S = Q K^T
    f32x4 s[2][4];
    for (int m = 0; m < 2; ++m)
      for (int n = 0; n < 4; ++n) s[m][n] = f32x4{0.f, 0.f, 0.f, 0.f};
    for (int kd = 0; kd < 4; ++kd) {
      bf16x8 kf[4];
      for (int n = 0; n < 4; ++n) {
        int kr = n * 16 + lrow;
        kf[n] = *(const bf16x8*)((char*)Ks +
                                 ((kr * 256 + kd * 64 + lk * 16) ^ ((kr & 7) << 4)));
      }
      for (int n = 0; n < 4; ++n) {
        if (actA) s[0][n] = mfma16(qreg[0][kd], kf[n], s[0][n]);
        s[1][n] = mfma16(qreg[1][kd], kf[n], s[1][n]);
      }
    }

    // online softmax (defer-max) + P write
    for (int m = 0; m < 2; ++m) {
      if (m == 0 && !actA) continue;
      const bool needMask = (m == 0) ? (t == tA - 1) : (t == tB - 1);
      for (int r = 0; r < 4; ++r) {
        const int qg = qbase[m] + lk * 4 + r;
        float v[4];
        for (int n = 0; n < 4; ++n) {
          float val = s[m][n][r] * ATT_SCALE;
          if (needMask && (kv0 + n * 16 + lrow > qg)) val = -1e30f;
          v[n] = val;
        }
        float mx = fmaxf(fmaxf(v[0], v[1]), fmaxf(v[2], v[3]));
        for (int off = 1; off < 16; off <<= 1) mx = fmaxf(mx, __shfl_xor(mx, off));
        if (mx > mst[m][r] + 8.f) {
          float alpha = __expf(mst[m][r] - mx);
          mst[m][r] = mx;
          lst[m][r] *= alpha;
          for (int df = 0; df < 8; ++df) acc[m][df][r] *= alpha;
        }
        float rs = 0.f;
        for (int n = 0; n < 4; ++n) {
          float pv = __expf(v[n] - mst[m][r]);
          s[m][n][r] = pv;
          rs += pv;
        }
        for (int off = 1; off < 16; off <<= 1) rs += __shfl_xor(rs, off);
        lst[m][r] += rs;
      }
      bf16_t* ps = &Ps[wid][0];
      for (int n = 0; n < 4; ++n)
        for (int r = 0; r < 4; ++r) {
          int row = m * 16 + lk * 4 + r, col = n * 16 + lrow;
          *(bf16_t*)((char*)ps + ((row * 128 + col * 2) ^ ((row & 7) << 4))) =
              (bf16_t)s[m][n][r];
        }
    }

    // O += P * V
    {
      bf16_t* ps = &Ps[wid][0];
      for (int kc = 0; kc < 2; ++kc) {
        bf16x8 pa[2];
        for (int m = 0; m < 2; ++m) {
          if (m == 0 && !actA) continue;
          int row = m * 16 + lrow;
          pa[m] = *(const bf16x8*)((char*)ps + ((row * 128 + kc * 64 + lk * 16) ^
                                                ((row & 7) << 4)));
        }
        for (int df = 0; df < 8; ++df) {
          int d = df * 16 + lrow;
          bf16x8 vb = *(const bf16x8*)((char*)Vs + ((d * 128 + kc * 64 + lk * 16) ^
                                                    ((d & 7) << 4)));
          if (actA) acc[0][df] = mfma16(pa[0], vb, acc[0][df]);
          acc[1][df] = mfma16(pa[1], vb, acc[1][df]);
        }
      }
    }

    if (haveNext) {
      __syncthreads();   // all waves done reading tile t
      for (int i = 0; i < 8; ++i) {
        *(bf16x8*)((char*)Ks + ((krow[i] * 256 + kcol[i] * 16) ^ ((krow[i] & 7) << 4))) = kpre[i];
        *(bf16x8*)((char*)Vs + ((vrow[i] * 128 + vcol[i] * 16) ^ ((vrow[i] & 7) << 4))) = vpre[i];
      }
      __syncthreads();   // tile t+1 visible
    }
  }

  // epilogue: O /= l, write bf16
  for (int m = 0; m < 2; ++m)
    for (int r = 0; r < 4; ++r) {
      float inv = 1.f / lst[m][r];
      int row = qbase[m] + lk * 4 + r;
      for (int df = 0; df < 8; ++df) {
        int col = h * HD + df * 16 + lrow;
        attn_out[(size_t)row * HID + col] = (bf16_t)(acc[m][df][r] * inv);
      }
    }
}

// ---------------- launch ----------------
extern "C" void kernel_launch(void* const* d_in, const int* in_sizes, int n_in,
                              void* d_out, int out_size, void* d_ws, size_t ws_size,
                              hipStream_t stream) {
  const int*   positions = (const int*)d_in[0];
  const float* hs        = (const float*)d_in[1];
  const float* wqkv      = (const float*)d_in[2];
  const float* wo        = (const float*)d_in[3];
  float*       out       = (float*)d_out;
  char* ws = (char*)d_ws;

  bf16_t* hsb   = (bf16_t*)(ws + 0);                 // 16,777,216
  bf16_t* wqkvt = (bf16_t*)(ws + 16777216);          // 50,331,648  [6144][4096]
  bf16_t* wot   = (bf16_t*)(ws + 67108864);          // 33,554,432  [4096][4096]
  bf16_t* qkv   = (bf16_t*)(ws + 100663296);         // 25,165,824  [2048][6144]
  float*  ct    = (float*)(ws + 125829120);          // 524,288
  float*  st    = (float*)(ws + 126353408);          // 524,288
  bf16_t* vtb   = (bf16_t*)(ws + 126877696);         // 4,194,304   [1024][2048]
  bf16_t* attn  = (bf16_t*)(ws + 131072000);         // 16,777,216  [2048][4096]

  cast_f32_bf16<<<4096, 256, 0, stream>>>(hs, hsb, SEQ * HID);
  transpose_cast<<<dim3(192, 128), dim3(32, 8), 0, stream>>>(wqkv, wqkvt, HID, QKV_N);
  transpose_cast<<<dim3(128, 128), dim3(32, 8), 0, stream>>>(wo, wot, HID, HID);
  rope_tables<<<512, 256, 0, stream>>>(positions, ct, st);

  gemm_bt<bf16_t><<<dim3(48, 16), 256, 0, stream>>>(hsb, wqkvt, qkv, SEQ, QKV_N, HID);

  rope_apply<<<20480, 256, 0, stream>>>(qkv, ct, st);
  transpose_v<<<dim3(32, 64), dim3(32, 8), 0, stream>>>(qkv, vtb);

  flash_attn<<<1024, 128, 0, stream>>>(qkv, vtb, attn);

  gemm_bt<float><<<dim3(32, 16), 256, 0, stream>>>(attn, wot, out, SEQ, HID, HID);
}

// Round 6
// 649.209 us; speedup vs baseline: 1.7023x; 1.7023x over previous
//
#include <hip/hip_runtime.h>
#include <cmath>

typedef __bf16 bf16_t;
typedef __bf16 bf16x8 __attribute__((ext_vector_type(8)));
typedef float  f32x4  __attribute__((ext_vector_type(4)));

#define SEQ    2048
#define HID    4096
#define QKV_N  6144
#define NH     32
#define NKV    8
#define HD     128
#define ATT_SCALE 0.08838834764831845f

__device__ __forceinline__ f32x4 mfma16(bf16x8 a, bf16x8 b, f32x4 c) {
  return __builtin_amdgcn_mfma_f32_16x16x32_bf16(a, b, c, 0, 0, 0);
}

__device__ __forceinline__ void gload_lds16(const void* g, void* l) {
  __builtin_amdgcn_global_load_lds(
      (const __attribute__((address_space(1))) void*)g,
      (__attribute__((address_space(3))) void*)l, 16, 0, 0);
}

// ---------------- cast fp32 -> bf16 (vectorized) ----------------
__global__ __launch_bounds__(256) void cast_f32_bf16(
    const float* __restrict__ in, bf16_t* __restrict__ out, int n) {
  int i = (blockIdx.x * 256 + threadIdx.x) * 8;
  if (i >= n) return;
  float4 v0 = *(const float4*)(in + i);
  float4 v1 = *(const float4*)(in + i + 4);
  bf16x8 o;
  o[0] = (bf16_t)v0.x; o[1] = (bf16_t)v0.y; o[2] = (bf16_t)v0.z; o[3] = (bf16_t)v0.w;
  o[4] = (bf16_t)v1.x; o[5] = (bf16_t)v1.y; o[6] = (bf16_t)v1.z; o[7] = (bf16_t)v1.w;
  *(bf16x8*)(out + i) = o;
}

// ---------------- transpose + cast: in [R][C] f32 -> out [C][R] bf16 ----------------
__global__ __launch_bounds__(256) void transpose_cast(
    const float* __restrict__ in, bf16_t* __restrict__ out, int R, int C) {
  __shared__ float tile[32][33];
  int c0 = blockIdx.x * 32, r0 = blockIdx.y * 32;
  int x = threadIdx.x, y = threadIdx.y;   // 32 x 8
  for (int j = 0; j < 32; j += 8)
    tile[y + j][x] = in[(size_t)(r0 + y + j) * C + c0 + x];
  __syncthreads();
  for (int j = 0; j < 32; j += 8)
    out[(size_t)(c0 + y + j) * R + r0 + x] = (bf16_t)tile[x][y + j];
}

// ---------------- transpose V part of qkv (bf16): [s][5120+dcol] -> vt[dcol][s] ----------------
__global__ __launch_bounds__(256) void transpose_v(
    const bf16_t* __restrict__ qkv, bf16_t* __restrict__ vt) {
  __shared__ bf16_t tile[32][33];
  int c0 = blockIdx.x * 32, r0 = blockIdx.y * 32;  // c0: dcol, r0: s
  int x = threadIdx.x, y = threadIdx.y;
  for (int j = 0; j < 32; j += 8)
    tile[y + j][x] = qkv[(size_t)(r0 + y + j) * QKV_N + 5120 + c0 + x];
  __syncthreads();
  for (int j = 0; j < 32; j += 8)
    vt[(size_t)(c0 + y + j) * SEQ + r0 + x] = tile[x][y + j];
}

// ---------------- RoPE cos/sin tables ----------------
__global__ __launch_bounds__(256) void rope_tables(
    const int* __restrict__ pos, float* __restrict__ ct, float* __restrict__ st) {
  int idx = blockIdx.x * 256 + threadIdx.x;
  if (idx >= SEQ * 64) return;
  int s = idx >> 6, j = idx & 63;
  double inv = exp(-((double)(2 * j) / 128.0) * log(10000.0));
  double a = (double)pos[s] * inv;
  ct[idx] = (float)cos(a);
  st[idx] = (float)sin(a);
}

// ---------------- apply RoPE in-place to q,k columns of qkv ----------------
__global__ __launch_bounds__(256) void rope_apply(
    bf16_t* __restrict__ qkv, const float* __restrict__ ct, const float* __restrict__ st) {
  int idx = blockIdx.x * 256 + threadIdx.x;   // SEQ * 2560
  int s = idx / 2560, p = idx % 2560;
  int head = p >> 6, j = p & 63;              // heads 0..31 = q, 32..39 = k
  int base = (head < NH) ? head * HD : HID + (head - NH) * HD;
  size_t o1 = (size_t)s * QKV_N + base + j;
  float x1 = (float)qkv[o1], x2 = (float)qkv[o1 + 64];
  float c = ct[s * 64 + j], sn = st[s * 64 + j];
  qkv[o1]      = (bf16_t)(x1 * c - x2 * sn);
  qkv[o1 + 64] = (bf16_t)(x2 * c + x1 * sn);
}

// ---------------- GEMM: C[M][N] = A[M][K] * Bt[N][K]^T  (m97 structure + XCD swz) ----------------
template <typename OutT>
__global__ __launch_bounds__(256, 2) void gemm_bt(
    const bf16_t* __restrict__ A, const bf16_t* __restrict__ Bt,
    OutT* __restrict__ C, int M, int N, int K) {
  __shared__ bf16_t As[128 * 32];
  __shared__ bf16_t Bs[128 * 32];
  const int tid = threadIdx.x;
  const int wid = tid >> 6, lane = tid & 63;
  // XCD-aware bijective swizzle (grid count is a multiple of 8)
  const int gx = gridDim.x;
  const int nwg = gx * gridDim.y;
  const int flat = blockIdx.y * gx + blockIdx.x;
  const int swz = (flat & 7) * (nwg >> 3) + (flat >> 3);
  const int m0 = (swz / gx) * 128, n0 = (swz % gx) * 128;
  const int wr = (wid >> 1) * 64, wc = (wid & 1) * 64;
  const int lrow = lane & 15, lk = lane >> 4;
  f32x4 acc[4][4];
  for (int m = 0; m < 4; ++m)
    for (int n = 0; n < 4; ++n) acc[m][n] = f32x4{0.f, 0.f, 0.f, 0.f};

  for (int k0 = 0; k0 < K; k0 += 32) {
    for (int i = 0; i < 2; ++i) {
      int off = wid * 2048 + i * 1024 + lane * 16;  // byte offset in 8KB tile
      int row = off >> 6;                            // 64B per row (32 bf16)
      int kk = (off & 63) >> 1;                      // element col
      gload_lds16(A + (size_t)(m0 + row) * K + k0 + kk,
                  (char*)As + wid * 2048 + i * 1024);
      gload_lds16(Bt + (size_t)(n0 + row) * K + k0 + kk,
                  (char*)Bs + wid * 2048 + i * 1024);
    }
    __syncthreads();
    bf16x8 a[4], b[4];
    for (int m = 0; m < 4; ++m)
      a[m] = *(const bf16x8*)(As + (wr + m * 16 + lrow) * 32 + lk * 8);
    for (int n = 0; n < 4; ++n)
      b[n] = *(const bf16x8*)(Bs + (wc + n * 16 + lrow) * 32 + lk * 8);
    for (int m = 0; m < 4; ++m)
      for (int n = 0; n < 4; ++n)
        acc[m][n] = mfma16(a[m], b[n], acc[m][n]);
    __syncthreads();
  }
  for (int m = 0; m < 4; ++m)
    for (int n = 0; n < 4; ++n)
      for (int r = 0; r < 4; ++r) {
        int row = m0 + wr + m * 16 + lk * 4 + r;
        int col = n0 + wc + n * 16 + lrow;
        C[(size_t)row * N + col] = (OutT)acc[m][n][r];
      }
}

// ---------------- flash attention (causal, GQA) ----------------
// 2-wave blocks, paired q-units (p, 63-p) -> constant work per block.
// kvh = bid&7 pins each kv-head's K/V to one XCD L2.
// K/V staged via global_load_lds (zero VGPR cost, no spills):
// linear LDS dest + pre-swizzled global source; reads use XOR swizzle.
__global__ __launch_bounds__(128, 2) void flash_attn(
    const bf16_t* __restrict__ qkv, const bf16_t* __restrict__ vt,
    bf16_t* __restrict__ attn_out) {
  __shared__ bf16_t Ks[64 * 128];    // [kv][d], phys-swizzled, 16KB
  __shared__ bf16_t Vs[128 * 64];    // [d][kv], phys-swizzled, 16KB
  __shared__ bf16_t Ps[2][32 * 64];  // per-wave P, swizzled, 8KB
  const int bid = blockIdx.x;
  const int kvh = bid & 7;
  const int u = bid >> 3;
  const int h = kvh * 4 + (u & 3);
  const int p = u >> 2;              // 0..31
  const int jA = p, jB = 63 - p;     // paired q-units of 32 rows
  const int tA = (jA >> 1) + 1, tB = (jB >> 1) + 1;
  const int tid = threadIdx.x, wid = tid >> 6, lane = tid & 63;
  const int lrow = lane & 15, lk = lane >> 4;
  const int qbase[2] = {jA * 32 + wid * 16, jB * 32 + wid * 16};

  // Q in registers
  bf16x8 qreg[2][4];
  for (int m = 0; m < 2; ++m)
    for (int kd = 0; kd < 4; ++kd)
      qreg[m][kd] = *(const bf16x8*)(qkv + (size_t)(qbase[m] + lrow) * QKV_N +
                                     h * HD + kd * 32 + lk * 8);

  f32x4 acc[2][8];
  float mst[2][4], lst[2][4];
  for (int m = 0; m < 2; ++m) {
    for (int df = 0; df < 8; ++df) acc[m][df] = f32x4{0.f, 0.f, 0.f, 0.f};
    for (int r = 0; r < 4; ++r) { mst[m][r] = -1e30f; lst[m][r] = 0.f; }
  }

  for (int t = 0; t < tB; ++t) {
    const int kv0 = t * 64;

    // stage tile t: linear LDS dest, inverse-swizzled global source.
    // LDS phys slot (row, pc) holds global chunk pc ^ (row&7); the
    // swizzled reads below then fetch logical chunks correctly.
    for (int i = 0; i < 8; ++i) {
      int idx = wid * 512 + i * 64 + lane;          // 16B-chunk index 0..1023
      int kr = idx >> 4, kc = (idx & 15) ^ (kr & 7);  // K: 64 rows x 16 chunks
      gload_lds16(qkv + (size_t)(kv0 + kr) * QKV_N + HID + kvh * HD + kc * 8,
                  (char*)Ks + wid * 8192 + i * 1024);
      int vd = idx >> 3, vc = (idx & 7) ^ (vd & 7);   // V: 128 rows x 8 chunks
      gload_lds16(vt + (size_t)(kvh * HD + vd) * SEQ + kv0 + vc * 8,
                  (char*)Vs + wid * 8192 + i * 1024);
    }
    __syncthreads();

    const bool actA = (t < tA);

    // S = Q K^T
    f32x4 s[2][4];
    for (int m = 0; m < 2; ++m)
      for (int n = 0; n < 4; ++n) s[m][n] = f32x4{0.f, 0.f, 0.f, 0.f};
    for (int kd = 0; kd < 4; ++kd) {
      bf16x8 kf[4];
      for (int n = 0; n < 4; ++n) {
        int kr = n * 16 + lrow;
        kf[n] = *(const bf16x8*)((char*)Ks +
                                 ((kr * 256 + kd * 64 + lk * 16) ^ ((kr & 7) << 4)));
      }
      for (int n = 0; n < 4; ++n) {
        if (actA) s[0][n] = mfma16(qreg[0][kd], kf[n], s[0][n]);
        s[1][n] = mfma16(qreg[1][kd], kf[n], s[1][n]);
      }
    }

    // online softmax (defer-max) + P write
    for (int m = 0; m < 2; ++m) {
      if (m == 0 && !actA) continue;
      const bool needMask = (m == 0) ? (t == tA - 1) : (t == tB - 1);
      for (int r = 0; r < 4; ++r) {
        const int qg = qbase[m] + lk * 4 + r;
        float v[4];
        for (int n = 0; n < 4; ++n) {
          float val = s[m][n][r] * ATT_SCALE;
          if (needMask && (kv0 + n * 16 + lrow > qg)) val = -1e30f;
          v[n] = val;
        }
        float mx = fmaxf(fmaxf(v[0], v[1]), fmaxf(v[2], v[3]));
        for (int off = 1; off < 16; off <<= 1) mx = fmaxf(mx, __shfl_xor(mx, off));
        if (mx > mst[m][r] + 8.f) {
          float alpha = __expf(mst[m][r] - mx);
          mst[m][r] = mx;
          lst[m][r] *= alpha;
          for (int df = 0; df < 8; ++df) acc[m][df][r] *= alpha;
        }
        float rs = 0.f;
        for (int n = 0; n < 4; ++n) {
          float pv = __expf(v[n] - mst[m][r]);
          s[m][n][r] = pv;
          rs += pv;
        }
        for (int off = 1; off < 16; off <<= 1) rs += __shfl_xor(rs, off);
        lst[m][r] += rs;
      }
      bf16_t* ps = &Ps[wid][0];
      for (int n = 0; n < 4; ++n)
        for (int r = 0; r < 4; ++r) {
          int row = m * 16 + lk * 4 + r, col = n * 16 + lrow;
          *(bf16_t*)((char*)ps + ((row * 128 + col * 2) ^ ((row & 7) << 4))) =
              (bf16_t)s[m][n][r];
        }
    }

    // O += P * V
    {
      bf16_t* ps = &Ps[wid][0];
      for (int kc = 0; kc < 2; ++kc) {
        bf16x8 pa[2];
        for (int m = 0; m < 2; ++m) {
          if (m == 0 && !actA) continue;
          int row = m * 16 + lrow;
          pa[m] = *(const bf16x8*)((char*)ps + ((row * 128 + kc * 64 + lk * 16) ^
                                                ((row & 7) << 4)));
        }
        for (int df = 0; df < 8; ++df) {
          int d = df * 16 + lrow;
          bf16x8 vb = *(const bf16x8*)((char*)Vs + ((d * 128 + kc * 64 + lk * 16) ^
                                                    ((d & 7) << 4)));
          if (actA) acc[0][df] = mfma16(pa[0], vb, acc[0][df]);
          acc[1][df] = mfma16(pa[1], vb, acc[1][df]);
        }
      }
    }

    __syncthreads();   // all waves done with tile t before next stage
  }

  // epilogue: O /= l, write bf16
  for (int m = 0; m < 2; ++m)
    for (int r = 0; r < 4; ++r) {
      float inv = 1.f / lst[m][r];
      int row = qbase[m] + lk * 4 + r;
      for (int df = 0; df < 8; ++df) {
        int col = h * HD + df * 16 + lrow;
        attn_out[(size_t)row * HID + col] = (bf16_t)(acc[m][df][r] * inv);
      }
    }
}

// ---------------- launch ----------------
extern "C" void kernel_launch(void* const* d_in, const int* in_sizes, int n_in,
                              void* d_out, int out_size, void* d_ws, size_t ws_size,
                              hipStream_t stream) {
  const int*   positions = (const int*)d_in[0];
  const float* hs        = (const float*)d_in[1];
  const float* wqkv      = (const float*)d_in[2];
  const float* wo        = (const float*)d_in[3];
  float*       out       = (float*)d_out;
  char* ws = (char*)d_ws;

  bf16_t* hsb   = (bf16_t*)(ws + 0);                 // 16,777,216
  bf16_t* wqkvt = (bf16_t*)(ws + 16777216);          // 50,331,648  [6144][4096]
  bf16_t* wot   = (bf16_t*)(ws + 67108864);          // 33,554,432  [4096][4096]
  bf16_t* qkv   = (bf16_t*)(ws + 100663296);         // 25,165,824  [2048][6144]
  float*  ct    = (float*)(ws + 125829120);          // 524,288
  float*  st    = (float*)(ws + 126353408);          // 524,288
  bf16_t* vtb   = (bf16_t*)(ws + 126877696);         // 4,194,304   [1024][2048]
  bf16_t* attn  = (bf16_t*)(ws + 131072000);         // 16,777,216  [2048][4096]

  cast_f32_bf16<<<4096, 256, 0, stream>>>(hs, hsb, SEQ * HID);
  transpose_cast<<<dim3(192, 128), dim3(32, 8), 0, stream>>>(wqkv, wqkvt, HID, QKV_N);
  transpose_cast<<<dim3(128, 128), dim3(32, 8), 0, stream>>>(wo, wot, HID, HID);
  rope_tables<<<512, 256, 0, stream>>>(positions, ct, st);

  gemm_bt<bf16_t><<<dim3(48, 16), 256, 0, stream>>>(hsb, wqkvt, qkv, SEQ, QKV_N, HID);

  rope_apply<<<20480, 256, 0, stream>>>(qkv, ct, st);
  transpose_v<<<dim3(32, 64), dim3(32, 8), 0, stream>>>(qkv, vtb);

  flash_attn<<<1024, 128, 0, stream>>>(qkv, vtb, attn);

  gemm_bt<float><<<dim3(32, 16), 256, 0, stream>>>(attn, wot, out, SEQ, HID, HID);
}